// Round 6
// baseline (145.216 us; speedup 1.0000x reference)
//
#include <hip/hip_runtime.h>
#include <math.h>

typedef unsigned short u16;
typedef __bf16 bf16x8 __attribute__((ext_vector_type(8)));
typedef float f32x4 __attribute__((ext_vector_type(4)));

#define T_TOKENS 4096   // B*S
#define D_DIM    512
#define H_DIM    2048
#define E_NUM    8
#define CAP      4096   // per-expert worst-case capacity
#define NSLOT    (T_TOKENS * 2)
#define NCHUNK   16     // compaction chunks of 256 tokens

__device__ __forceinline__ u16 f2bf(float f) {
  unsigned int u = __builtin_bit_cast(unsigned int, f);
  u = (u + 0x7fffu + ((u >> 16) & 1u)) >> 16;   // RNE
  return (u16)u;
}

__device__ __forceinline__ void gload16(const void* g, void* l) {
  __builtin_amdgcn_global_load_lds(
      (__attribute__((address_space(1))) void*)(g),
      (__attribute__((address_space(3))) void*)(l), 16, 0, 0);
}

// gelu(v) ~= v * sigmoid(v*(1.59576912 + 0.071354817*v^2)); rcp instead of slow f32 div
__device__ __forceinline__ float gelu_fast(float v) {
  float u = v * __fmaf_rn(0.071354817f, v * v, 1.59576912f);
  float e = __expf(-u);
  return v * __builtin_amdgcn_rcpf(1.0f + e);
}

// ---------------- both weights: f32 [E][R][C] -> bf16 [E][C][R], one launch ----------------
__global__ __launch_bounds__(256) void transpose_both_kernel(const float* __restrict__ w1,
                                                             const float* __restrict__ w2,
                                                             u16* __restrict__ w1t,
                                                             u16* __restrict__ w2t) {
  __shared__ float tile[64][67];
  int bid = blockIdx.x;
  const float* in; u16* out; int R, C;
  if (bid < 2048) { in = w1; out = w1t; R = D_DIM; C = H_DIM; }
  else            { bid -= 2048; in = w2; out = w2t; R = H_DIM; C = D_DIM; }
  const int e = bid >> 8;
  const int t = bid & 255;
  const int nCx = C >> 6;
  const int c0 = (t % nCx) * 64, r0 = (t / nCx) * 64;
  const float* src = in + (size_t)e * D_DIM * H_DIM;
  u16* dst = out + (size_t)e * D_DIM * H_DIM;
  const int tid = threadIdx.x;
  {
    const int row = tid >> 2, cc = (tid & 3) * 16;
    const float* s = src + (size_t)(r0 + row) * C + c0 + cc;
#pragma unroll
    for (int j = 0; j < 4; j++)
      *(float4*)(&tile[row][cc + 4 * j]) = *(const float4*)(s + 4 * j);
  }
  __syncthreads();
  {
    const int c = tid >> 2, rc = (tid & 3) * 16;
    u16 buf[16];
#pragma unroll
    for (int j = 0; j < 16; j++) buf[j] = f2bf(tile[rc + j][c]);
    u16* d = dst + (size_t)(c0 + c) * R + r0 + rc;
    *(uint4*)(d)     = *(uint4*)(&buf[0]);
    *(uint4*)(d + 8) = *(uint4*)(&buf[8]);
  }
}

// ---------------- router + x->bf16 + zero(out) ----------------
__global__ __launch_bounds__(256) void router_kernel(const float* __restrict__ x,
                                                     const float* __restrict__ rw,
                                                     const float* __restrict__ rb,
                                                     int* __restrict__ topk_idx,
                                                     float* __restrict__ topk_p,
                                                     u16* __restrict__ xb,
                                                     float* __restrict__ outz) {
  {
    float4 z = {0.f, 0.f, 0.f, 0.f};
    float4* o = (float4*)(outz + (size_t)blockIdx.x * 2048);
    o[threadIdx.x] = z;
    o[threadIdx.x + 256] = z;
  }
  const int lane = threadIdx.x & 63;
  const int t = blockIdx.x * 4 + (threadIdx.x >> 6);
  const float* xr = x + (size_t)t * D_DIM + lane * 8;
  float xv[8];
  *(float4*)(&xv[0]) = *(const float4*)(xr);
  *(float4*)(&xv[4]) = *(const float4*)(xr + 4);
  ushort4 o0, o1;
  o0.x = f2bf(xv[0]); o0.y = f2bf(xv[1]); o0.z = f2bf(xv[2]); o0.w = f2bf(xv[3]);
  o1.x = f2bf(xv[4]); o1.y = f2bf(xv[5]); o1.z = f2bf(xv[6]); o1.w = f2bf(xv[7]);
  ushort4* xo = (ushort4*)(xb + (size_t)t * D_DIM + lane * 8);
  xo[0] = o0; xo[1] = o1;

  float acc[8] = {0.f,0.f,0.f,0.f,0.f,0.f,0.f,0.f};
#pragma unroll
  for (int j = 0; j < 8; j++) {
    const float4* w = (const float4*)(rw + (size_t)(lane * 8 + j) * E_NUM);
    float4 w0 = w[0], w1 = w[1];
    acc[0] += xv[j] * w0.x; acc[1] += xv[j] * w0.y;
    acc[2] += xv[j] * w0.z; acc[3] += xv[j] * w0.w;
    acc[4] += xv[j] * w1.x; acc[5] += xv[j] * w1.y;
    acc[6] += xv[j] * w1.z; acc[7] += xv[j] * w1.w;
  }
#pragma unroll
  for (int off = 32; off > 0; off >>= 1) {
#pragma unroll
    for (int e = 0; e < 8; e++) acc[e] += __shfl_down(acc[e], off);
  }
  if (lane == 0) {
    float l[8];
#pragma unroll
    for (int e = 0; e < 8; e++) l[e] = acc[e] + rb[e];
    int i0 = 0; float v0 = l[0];
#pragma unroll
    for (int e = 1; e < 8; e++) if (l[e] > v0) { v0 = l[e]; i0 = e; }
    int i1 = -1; float v1 = -3.4e38f;
#pragma unroll
    for (int e = 0; e < 8; e++) if (e != i0 && l[e] > v1) { v1 = l[e]; i1 = e; }
    float p1 = expf(v1 - v0);
    float s = 1.0f + p1;
    topk_idx[t * 2] = i0; topk_idx[t * 2 + 1] = i1;
    topk_p[t * 2] = 1.0f / s; topk_p[t * 2 + 1] = p1 / s;
  }
}

// ---------------- compaction phase 1: per-chunk per-expert counts ----------------
__global__ __launch_bounds__(256) void count_kernel(const int* __restrict__ topk_idx,
                                                    int* __restrict__ chunkcnt) {  // [NCHUNK][E]
  const int b = blockIdx.x, tid = threadIdx.x, lane = tid & 63, w = tid >> 6;
  const int t = b * 256 + tid;
  const int i0 = topk_idx[t * 2], i1 = topk_idx[t * 2 + 1];
  __shared__ int ws[4][E_NUM];
#pragma unroll
  for (int e = 0; e < E_NUM; e++) {
    unsigned long long m = __ballot(i0 == e || i1 == e);
    if (lane == 0) ws[w][e] = (int)__popcll(m);
  }
  __syncthreads();
  if (tid < E_NUM)
    chunkcnt[b * E_NUM + tid] = ws[0][tid] + ws[1][tid] + ws[2][tid] + ws[3][tid];
}

// ---------------- compaction phase 2: prefix + scatter (deterministic) ----------------
__global__ __launch_bounds__(256) void scatter_kernel(const int* __restrict__ topk_idx,
                                                      const float* __restrict__ topk_p,
                                                      const int* __restrict__ chunkcnt,
                                                      int* __restrict__ slot_list,
                                                      float* __restrict__ prob_list,
                                                      int* __restrict__ counts) {
  const int e = blockIdx.x & 7, chunk = blockIdx.x >> 3;
  const int tid = threadIdx.x, lane = tid & 63, w = tid >> 6;
  int base = 0;
  for (int c = 0; c < chunk; ++c) base += chunkcnt[c * E_NUM + e];
  const int t = chunk * 256 + tid;
  const int i0 = topk_idx[t * 2], i1 = topk_idx[t * 2 + 1];
  int flag = 0, slot = 0; float p = 0.f;
  if (i0 == e)      { flag = 1; slot = t * 2;     p = topk_p[t * 2]; }
  else if (i1 == e) { flag = 1; slot = t * 2 + 1; p = topk_p[t * 2 + 1]; }
  unsigned long long m = __ballot(flag);
  __shared__ int wsum[4];
  if (lane == 0) wsum[w] = (int)__popcll(m);
  const int wpre = (int)__popcll(m & ((1ull << lane) - 1ull));
  __syncthreads();
  int wb = base;
#pragma unroll
  for (int j = 0; j < 4; j++) if (j < w) wb += wsum[j];
  if (flag) { slot_list[e * CAP + wb + wpre] = slot; prob_list[e * CAP + wb + wpre] = p; }
  if (chunk == NCHUNK - 1 && tid == 0)
    counts[e] = base + wsum[0] + wsum[1] + wsum[2] + wsum[3];
}

// ---------------- grouped GEMM1: h = gelu(x @ w1 + b1) * p ----------------
// tile 64x128, BK=64, 3-buffer 2-deep prefetch, T2 swizzle, expert->XCD swizzle
// grid: flat 8192 = e(8) x rt(64) x cx(16), e = bid&7
__global__ __launch_bounds__(256, 2) void gemm1_kernel(const u16* __restrict__ xb,
                                                       const u16* __restrict__ w1t,   // [E][H][D]
                                                       const float* __restrict__ b1,  // [E][H]
                                                       const int* __restrict__ slot_list,
                                                       const float* __restrict__ prob_list,
                                                       const int* __restrict__ counts,
                                                       u16* __restrict__ hbuf) {      // [2T][H]
  const int f = blockIdx.x;
  const int e  = f & 7;
  const int g  = f >> 3;
  const int cx = g & 15;
  const int rt = g >> 4;           // 0..63
  const int cnt = counts[e];
  const int rbase = rt * 64;
  if (rbase >= cnt) return;
  const int n0 = cx * 128;

  __shared__ __align__(16) u16 At[3][64 * 64];
  __shared__ __align__(16) u16 Bt[3][128 * 64];

  const int tid = threadIdx.x, lane = tid & 63, wid = tid >> 6;
  const int wr = wid >> 1, wc = wid & 1;
  const int lr8 = lane >> 3;
  const int sx = lane & 7;
  const int kperm = (sx ^ lr8) * 8;
  const int lrow = lane & 15, lk = lane >> 4;

  const u16* pa[2]; int loa[2];
#pragma unroll
  for (int i = 0; i < 2; i++) {
    const int row = (wid * 2 + i) * 8 + lr8;          // 0..63
    const int grow = rbase + row;
    int tok = 0;
    if (grow < cnt) tok = slot_list[e * CAP + grow] >> 1;
    pa[i] = xb + (size_t)tok * D_DIM + kperm;
    loa[i] = (wid * 2 + i) * 512;
  }
  const u16* pb[4]; int lob[4];
#pragma unroll
  for (int i = 0; i < 4; i++) {
    const int row = (wid * 4 + i) * 8 + lr8;          // 0..127
    pb[i] = w1t + ((size_t)e * H_DIM + n0 + row) * D_DIM + kperm;
    lob[i] = (wid * 4 + i) * 512;
  }

  f32x4 acc[2][4];
#pragma unroll
  for (int i = 0; i < 2; i++)
#pragma unroll
    for (int j = 0; j < 4; j++) acc[i][j] = (f32x4){0.f, 0.f, 0.f, 0.f};

  auto stage = [&](int k0, int b) {   // 6 gload_lds per thread
#pragma unroll
    for (int i = 0; i < 2; i++) gload16(pa[i] + k0, &At[b][loa[i]]);
#pragma unroll
    for (int i = 0; i < 4; i++) gload16(pb[i] + k0, &Bt[b][lob[i]]);
  };

  stage(0, 0); stage(64, 1); stage(128, 2);
  const int nt = D_DIM / 64;   // 8
  int cur = 0;
  for (int t = 0; t < nt; ++t) {
    if (t < nt - 2)       { asm volatile("s_waitcnt vmcnt(12)" ::: "memory"); }
    else if (t == nt - 2) { asm volatile("s_waitcnt vmcnt(6)" ::: "memory"); }
    else                  { asm volatile("s_waitcnt vmcnt(0)" ::: "memory"); }
    __builtin_amdgcn_sched_barrier(0);
    __builtin_amdgcn_s_barrier();            // buf[cur] fully written, all waves
    bf16x8 afr[2][2], bfr[4][2];
#pragma unroll
    for (int ks = 0; ks < 2; ks++) {
#pragma unroll
      for (int fq = 0; fq < 2; fq++)
        afr[fq][ks] = *(const bf16x8*)(&At[cur][(wr * 32 + fq * 16 + lrow) * 64 + ((ks * 4 + lk) ^ sx) * 8]);
#pragma unroll
      for (int fq = 0; fq < 4; fq++)
        bfr[fq][ks] = *(const bf16x8*)(&Bt[cur][(wc * 64 + fq * 16 + lrow) * 64 + ((ks * 4 + lk) ^ sx) * 8]);
    }
    asm volatile("s_waitcnt lgkmcnt(0)" ::: "memory");
    __builtin_amdgcn_sched_barrier(0);
    __builtin_amdgcn_s_barrier();            // all waves done reading buf[cur]
    if (t + 3 < nt) stage((t + 3) * 64, cur);
    __builtin_amdgcn_sched_barrier(0);
    __builtin_amdgcn_s_setprio(1);
#pragma unroll
    for (int ks = 0; ks < 2; ks++)
#pragma unroll
      for (int fr = 0; fr < 2; fr++)
#pragma unroll
        for (int fc = 0; fc < 4; fc++)
          acc[fr][fc] = __builtin_amdgcn_mfma_f32_16x16x32_bf16(afr[fr][ks], bfr[fc][ks], acc[fr][fc], 0, 0, 0);
    __builtin_amdgcn_s_setprio(0);
    cur = (cur == 2) ? 0 : cur + 1;
  }

  float bias[4];
#pragma unroll
  for (int fc = 0; fc < 4; fc++) bias[fc] = b1[e * H_DIM + n0 + wc * 64 + fc * 16 + lrow];
#pragma unroll
  for (int fr = 0; fr < 2; fr++) {
#pragma unroll
    for (int reg = 0; reg < 4; reg++) {
      const int rloc = wr * 32 + fr * 16 + lk * 4 + reg;
      const int grow = rbase + rloc;
      if (grow < cnt) {
        const int slot = slot_list[e * CAP + grow];
        const float p  = prob_list[e * CAP + grow];
        u16* dst = hbuf + (size_t)slot * H_DIM + n0 + wc * 64 + lrow;
#pragma unroll
        for (int fc = 0; fc < 4; fc++) {
          float v = acc[fr][fc][reg] + bias[fc];
          dst[fc * 16] = f2bf(gelu_fast(v) * p);
        }
      }
    }
  }
}

// ---------------- grouped GEMM2: out[t] += h @ w2 + p*b2 (atomic f32, 2 addends) --------
// tile 64x128, BK=64, 3-buffer 2-deep prefetch, T2 swizzle, expert->XCD swizzle
// grid: flat 2048 = e(8) x rt(64) x cx(4), e = bid&7
__global__ __launch_bounds__(256, 2) void gemm2_kernel(const u16* __restrict__ hbuf,  // [2T][H]
                                                       const u16* __restrict__ w2t,   // [E][D][H]
                                                       const float* __restrict__ b2,  // [E][D]
                                                       const int* __restrict__ slot_list,
                                                       const float* __restrict__ prob_list,
                                                       const int* __restrict__ counts,
                                                       float* __restrict__ out) {     // [T][D]
  const int f = blockIdx.x;
  const int e  = f & 7;
  const int g  = f >> 3;
  const int cx = g & 3;
  const int rt = g >> 2;           // 0..63
  const int cnt = counts[e];
  const int rbase = rt * 64;
  if (rbase >= cnt) return;
  const int n0 = cx * 128;

  __shared__ __align__(16) u16 At[3][64 * 64];
  __shared__ __align__(16) u16 Bt[3][128 * 64];

  const int tid = threadIdx.x, lane = tid & 63, wid = tid >> 6;
  const int wr = wid >> 1, wc = wid & 1;
  const int lr8 = lane >> 3;
  const int sx = lane & 7;
  const int kperm = (sx ^ lr8) * 8;
  const int lrow = lane & 15, lk = lane >> 4;

  const u16* pa[2]; int loa[2];
#pragma unroll
  for (int i = 0; i < 2; i++) {
    const int row = (wid * 2 + i) * 8 + lr8;          // 0..63
    const int grow = rbase + row;
    int slot = 0;
    if (grow < cnt) slot = slot_list[e * CAP + grow];
    pa[i] = hbuf + (size_t)slot * H_DIM + kperm;
    loa[i] = (wid * 2 + i) * 512;
  }
  const u16* pb[4]; int lob[4];
#pragma unroll
  for (int i = 0; i < 4; i++) {
    const int row = (wid * 4 + i) * 8 + lr8;          // 0..127
    pb[i] = w2t + ((size_t)e * D_DIM + n0 + row) * H_DIM + kperm;
    lob[i] = (wid * 4 + i) * 512;
  }

  f32x4 acc[2][4];
#pragma unroll
  for (int i = 0; i < 2; i++)
#pragma unroll
    for (int j = 0; j < 4; j++) acc[i][j] = (f32x4){0.f, 0.f, 0.f, 0.f};

  auto stage = [&](int k0, int b) {   // 6 gload_lds per thread
#pragma unroll
    for (int i = 0; i < 2; i++) gload16(pa[i] + k0, &At[b][loa[i]]);
#pragma unroll
    for (int i = 0; i < 4; i++) gload16(pb[i] + k0, &Bt[b][lob[i]]);
  };

  stage(0, 0); stage(64, 1); stage(128, 2);
  const int nt = H_DIM / 64;   // 32
  int cur = 0;
  for (int t = 0; t < nt; ++t) {
    if (t < nt - 2)       { asm volatile("s_waitcnt vmcnt(12)" ::: "memory"); }
    else if (t == nt - 2) { asm volatile("s_waitcnt vmcnt(6)" ::: "memory"); }
    else                  { asm volatile("s_waitcnt vmcnt(0)" ::: "memory"); }
    __builtin_amdgcn_sched_barrier(0);
    __builtin_amdgcn_s_barrier();
    bf16x8 afr[2][2], bfr[4][2];
#pragma unroll
    for (int ks = 0; ks < 2; ks++) {
#pragma unroll
      for (int fq = 0; fq < 2; fq++)
        afr[fq][ks] = *(const bf16x8*)(&At[cur][(wr * 32 + fq * 16 + lrow) * 64 + ((ks * 4 + lk) ^ sx) * 8]);
#pragma unroll
      for (int fq = 0; fq < 4; fq++)
        bfr[fq][ks] = *(const bf16x8*)(&Bt[cur][(wc * 64 + fq * 16 + lrow) * 64 + ((ks * 4 + lk) ^ sx) * 8]);
    }
    asm volatile("s_waitcnt lgkmcnt(0)" ::: "memory");
    __builtin_amdgcn_sched_barrier(0);
    __builtin_amdgcn_s_barrier();
    if (t + 3 < nt) stage((t + 3) * 64, cur);
    __builtin_amdgcn_sched_barrier(0);
    __builtin_amdgcn_s_setprio(1);
#pragma unroll
    for (int ks = 0; ks < 2; ks++)
#pragma unroll
      for (int fr = 0; fr < 2; fr++)
#pragma unroll
        for (int fc = 0; fc < 4; fc++)
          acc[fr][fc] = __builtin_amdgcn_mfma_f32_16x16x32_bf16(afr[fr][ks], bfr[fc][ks], acc[fr][fc], 0, 0, 0);
    __builtin_amdgcn_s_setprio(0);
    cur = (cur == 2) ? 0 : cur + 1;
  }

  // epilogue: out[token] += acc + p*b2 (exactly 2 atomic addends per element -> deterministic)
#pragma unroll
  for (int fr = 0; fr < 2; fr++) {
#pragma unroll
    for (int reg = 0; reg < 4; reg++) {
      const int rloc = wr * 32 + fr * 16 + lk * 4 + reg;
      const int grow = rbase + rloc;
      if (grow < cnt) {
        const int slot = slot_list[e * CAP + grow];
        const float p  = prob_list[e * CAP + grow];
        float* dst = out + (size_t)(slot >> 1) * D_DIM + n0 + wc * 64 + lrow;
#pragma unroll
        for (int fc = 0; fc < 4; fc++) {
          float v = acc[fr][fc][reg] + p * b2[e * D_DIM + n0 + wc * 64 + fc * 16 + lrow];
          atomicAdd(&dst[fc * 16], v);
        }
      }
    }
  }
}

extern "C" void kernel_launch(void* const* d_in, const int* in_sizes, int n_in,
                              void* d_out, int out_size, void* d_ws, size_t ws_size,
                              hipStream_t stream) {
  const float* x  = (const float*)d_in[0];
  const float* w1 = (const float*)d_in[1];
  const float* w2 = (const float*)d_in[2];
  const float* b1 = (const float*)d_in[3];
  const float* b2 = (const float*)d_in[4];
  const float* rw = (const float*)d_in[5];
  const float* rb = (const float*)d_in[6];
  float* out = (float*)d_out;

  char* ws = (char*)d_ws;
  size_t off = 0;
  auto alloc = [&](size_t bytes) -> void* {
    void* p = ws + off;
    off = (off + bytes + 255) & ~(size_t)255;
    return p;
  };
  int*   counts    = (int*)alloc(E_NUM * 4);
  int*   chunkcnt  = (int*)alloc(NCHUNK * E_NUM * 4);
  int*   slot_list = (int*)alloc((size_t)E_NUM * CAP * 4);
  float* prob_list = (float*)alloc((size_t)E_NUM * CAP * 4);
  int*   topk_idx  = (int*)alloc((size_t)T_TOKENS * 2 * 4);
  float* topk_p    = (float*)alloc((size_t)T_TOKENS * 2 * 4);
  u16*   xb        = (u16*)alloc((size_t)T_TOKENS * D_DIM * 2);
  u16*   w1t       = (u16*)alloc((size_t)E_NUM * H_DIM * D_DIM * 2);
  u16*   w2t       = (u16*)alloc((size_t)E_NUM * H_DIM * D_DIM * 2);
  u16*   hbuf      = (u16*)alloc((size_t)NSLOT * H_DIM * 2);

  transpose_both_kernel<<<4096, 256, 0, stream>>>(w1, w2, w1t, w2t);
  router_kernel<<<T_TOKENS / 4, 256, 0, stream>>>(x, rw, rb, topk_idx, topk_p, xb, out);
  count_kernel<<<NCHUNK, 256, 0, stream>>>(topk_idx, chunkcnt);
  scatter_kernel<<<NCHUNK * E_NUM, 256, 0, stream>>>(topk_idx, topk_p, chunkcnt, slot_list, prob_list, counts);
  gemm1_kernel<<<E_NUM * 64 * 16, 256, 0, stream>>>(xb, w1t, b1, slot_list, prob_list, counts, hbuf);
  gemm2_kernel<<<E_NUM * 64 * 4, 256, 0, stream>>>(hbuf, w2t, b2, slot_list, prob_list, counts, out);
}

// Round 7
// 120.027 us; speedup vs baseline: 1.2099x; 1.2099x over previous
//
#include <hip/hip_runtime.h>
#include <math.h>

typedef unsigned short u16;
typedef __bf16 bf16x8 __attribute__((ext_vector_type(8)));
typedef float f32x4 __attribute__((ext_vector_type(4)));

#define T_TOKENS 4096   // B*S
#define D_DIM    512
#define H_DIM    2048
#define E_NUM    8
#define CAP      4096   // per-expert worst-case capacity
#define NSLOT    (T_TOKENS * 2)
#define NCHUNK   16     // compaction chunks of 256 tokens

__device__ __forceinline__ u16 f2bf(float f) {
  unsigned int u = __builtin_bit_cast(unsigned int, f);
  u = (u + 0x7fffu + ((u >> 16) & 1u)) >> 16;   // RNE
  return (u16)u;
}

__device__ __forceinline__ void gload16(const void* g, void* l) {
  __builtin_amdgcn_global_load_lds(
      (__attribute__((address_space(1))) void*)(g),
      (__attribute__((address_space(3))) void*)(l), 16, 0, 0);
}

// gelu(v) ~= v * sigmoid(v*(1.59576912 + 0.071354817*v^2)); rcp instead of slow f32 div
__device__ __forceinline__ float gelu_fast(float v) {
  float u = v * __fmaf_rn(0.071354817f, v * v, 1.59576912f);
  float e = __expf(-u);
  return v * __builtin_amdgcn_rcpf(1.0f + e);
}

// ---------------- both weights: f32 [E][R][C] -> bf16 [E][C][R], one launch ----------------
__global__ __launch_bounds__(256) void transpose_both_kernel(const float* __restrict__ w1,
                                                             const float* __restrict__ w2,
                                                             u16* __restrict__ w1t,
                                                             u16* __restrict__ w2t) {
  __shared__ float tile[64][67];
  int bid = blockIdx.x;
  const float* in; u16* out; int R, C;
  if (bid < 2048) { in = w1; out = w1t; R = D_DIM; C = H_DIM; }
  else            { bid -= 2048; in = w2; out = w2t; R = H_DIM; C = D_DIM; }
  const int e = bid >> 8;
  const int t = bid & 255;
  const int nCx = C >> 6;
  const int c0 = (t % nCx) * 64, r0 = (t / nCx) * 64;
  const float* src = in + (size_t)e * D_DIM * H_DIM;
  u16* dst = out + (size_t)e * D_DIM * H_DIM;
  const int tid = threadIdx.x;
  {
    const int row = tid >> 2, cc = (tid & 3) * 16;
    const float* s = src + (size_t)(r0 + row) * C + c0 + cc;
#pragma unroll
    for (int j = 0; j < 4; j++)
      *(float4*)(&tile[row][cc + 4 * j]) = *(const float4*)(s + 4 * j);
  }
  __syncthreads();
  {
    const int c = tid >> 2, rc = (tid & 3) * 16;
    u16 buf[16];
#pragma unroll
    for (int j = 0; j < 16; j++) buf[j] = f2bf(tile[rc + j][c]);
    u16* d = dst + (size_t)(c0 + c) * R + r0 + rc;
    *(uint4*)(d)     = *(uint4*)(&buf[0]);
    *(uint4*)(d + 8) = *(uint4*)(&buf[8]);
  }
}

// ---------------- router + x->bf16 + zero(out) ----------------
__global__ __launch_bounds__(256) void router_kernel(const float* __restrict__ x,
                                                     const float* __restrict__ rw,
                                                     const float* __restrict__ rb,
                                                     int* __restrict__ topk_idx,
                                                     float* __restrict__ topk_p,
                                                     u16* __restrict__ xb,
                                                     float* __restrict__ outz) {
  {
    float4 z = {0.f, 0.f, 0.f, 0.f};
    float4* o = (float4*)(outz + (size_t)blockIdx.x * 2048);
    o[threadIdx.x] = z;
    o[threadIdx.x + 256] = z;
  }
  const int lane = threadIdx.x & 63;
  const int t = blockIdx.x * 4 + (threadIdx.x >> 6);
  const float* xr = x + (size_t)t * D_DIM + lane * 8;
  float xv[8];
  *(float4*)(&xv[0]) = *(const float4*)(xr);
  *(float4*)(&xv[4]) = *(const float4*)(xr + 4);
  ushort4 o0, o1;
  o0.x = f2bf(xv[0]); o0.y = f2bf(xv[1]); o0.z = f2bf(xv[2]); o0.w = f2bf(xv[3]);
  o1.x = f2bf(xv[4]); o1.y = f2bf(xv[5]); o1.z = f2bf(xv[6]); o1.w = f2bf(xv[7]);
  ushort4* xo = (ushort4*)(xb + (size_t)t * D_DIM + lane * 8);
  xo[0] = o0; xo[1] = o1;

  float acc[8] = {0.f,0.f,0.f,0.f,0.f,0.f,0.f,0.f};
#pragma unroll
  for (int j = 0; j < 8; j++) {
    const float4* w = (const float4*)(rw + (size_t)(lane * 8 + j) * E_NUM);
    float4 w0 = w[0], w1 = w[1];
    acc[0] += xv[j] * w0.x; acc[1] += xv[j] * w0.y;
    acc[2] += xv[j] * w0.z; acc[3] += xv[j] * w0.w;
    acc[4] += xv[j] * w1.x; acc[5] += xv[j] * w1.y;
    acc[6] += xv[j] * w1.z; acc[7] += xv[j] * w1.w;
  }
#pragma unroll
  for (int off = 32; off > 0; off >>= 1) {
#pragma unroll
    for (int e = 0; e < 8; e++) acc[e] += __shfl_down(acc[e], off);
  }
  if (lane == 0) {
    float l[8];
#pragma unroll
    for (int e = 0; e < 8; e++) l[e] = acc[e] + rb[e];
    int i0 = 0; float v0 = l[0];
#pragma unroll
    for (int e = 1; e < 8; e++) if (l[e] > v0) { v0 = l[e]; i0 = e; }
    int i1 = -1; float v1 = -3.4e38f;
#pragma unroll
    for (int e = 0; e < 8; e++) if (e != i0 && l[e] > v1) { v1 = l[e]; i1 = e; }
    float p1 = expf(v1 - v0);
    float s = 1.0f + p1;
    topk_idx[t * 2] = i0; topk_idx[t * 2 + 1] = i1;
    topk_p[t * 2] = 1.0f / s; topk_p[t * 2 + 1] = p1 / s;
  }
}

// ---------------- compaction phase 1: per-chunk per-expert counts ----------------
__global__ __launch_bounds__(256) void count_kernel(const int* __restrict__ topk_idx,
                                                    int* __restrict__ chunkcnt) {  // [NCHUNK][E]
  const int b = blockIdx.x, tid = threadIdx.x, lane = tid & 63, w = tid >> 6;
  const int t = b * 256 + tid;
  const int i0 = topk_idx[t * 2], i1 = topk_idx[t * 2 + 1];
  __shared__ int ws[4][E_NUM];
#pragma unroll
  for (int e = 0; e < E_NUM; e++) {
    unsigned long long m = __ballot(i0 == e || i1 == e);
    if (lane == 0) ws[w][e] = (int)__popcll(m);
  }
  __syncthreads();
  if (tid < E_NUM)
    chunkcnt[b * E_NUM + tid] = ws[0][tid] + ws[1][tid] + ws[2][tid] + ws[3][tid];
}

// ---------------- compaction phase 2: prefix + scatter (deterministic) ----------------
__global__ __launch_bounds__(256) void scatter_kernel(const int* __restrict__ topk_idx,
                                                      const float* __restrict__ topk_p,
                                                      const int* __restrict__ chunkcnt,
                                                      int* __restrict__ slot_list,
                                                      float* __restrict__ prob_list,
                                                      int* __restrict__ counts) {
  const int e = blockIdx.x & 7, chunk = blockIdx.x >> 3;
  const int tid = threadIdx.x, lane = tid & 63, w = tid >> 6;
  int base = 0;
  for (int c = 0; c < chunk; ++c) base += chunkcnt[c * E_NUM + e];
  const int t = chunk * 256 + tid;
  const int i0 = topk_idx[t * 2], i1 = topk_idx[t * 2 + 1];
  int flag = 0, slot = 0; float p = 0.f;
  if (i0 == e)      { flag = 1; slot = t * 2;     p = topk_p[t * 2]; }
  else if (i1 == e) { flag = 1; slot = t * 2 + 1; p = topk_p[t * 2 + 1]; }
  unsigned long long m = __ballot(flag);
  __shared__ int wsum[4];
  if (lane == 0) wsum[w] = (int)__popcll(m);
  const int wpre = (int)__popcll(m & ((1ull << lane) - 1ull));
  __syncthreads();
  int wb = base;
#pragma unroll
  for (int j = 0; j < 4; j++) if (j < w) wb += wsum[j];
  if (flag) { slot_list[e * CAP + wb + wpre] = slot; prob_list[e * CAP + wb + wpre] = p; }
  if (chunk == NCHUNK - 1 && tid == 0)
    counts[e] = base + wsum[0] + wsum[1] + wsum[2] + wsum[3];
}

// ---------------- grouped GEMM1: h = gelu(x @ w1 + b1) * p ----------------
// tile 64x128, BK=64, 2-buffer single-barrier loop, T2 swizzle, 48KB -> 3 blocks/CU
// grid: dim3(16, E*64)
__global__ __launch_bounds__(256, 3) void gemm1_kernel(const u16* __restrict__ xb,
                                                       const u16* __restrict__ w1t,   // [E][H][D]
                                                       const float* __restrict__ b1,  // [E][H]
                                                       const int* __restrict__ slot_list,
                                                       const float* __restrict__ prob_list,
                                                       const int* __restrict__ counts,
                                                       u16* __restrict__ hbuf) {      // [2T][H]
  const int e  = blockIdx.y >> 6;
  const int rt = blockIdx.y & 63;
  const int cnt = counts[e];
  const int rbase = rt * 64;
  if (rbase >= cnt) return;
  const int n0 = blockIdx.x * 128;

  __shared__ __align__(16) u16 At[2][64 * 64];
  __shared__ __align__(16) u16 Bt[2][128 * 64];

  const int tid = threadIdx.x, lane = tid & 63, wid = tid >> 6;
  const int wr = wid >> 1, wc = wid & 1;
  const int lr8 = lane >> 3;
  const int sx = lane & 7;
  const int kperm = (sx ^ lr8) * 8;
  const int lrow = lane & 15, lk = lane >> 4;

  const u16* pa[2]; int loa[2];
#pragma unroll
  for (int i = 0; i < 2; i++) {
    const int row = (wid * 2 + i) * 8 + lr8;          // 0..63
    const int grow = rbase + row;
    int tok = 0;
    if (grow < cnt) tok = slot_list[e * CAP + grow] >> 1;
    pa[i] = xb + (size_t)tok * D_DIM + kperm;
    loa[i] = (wid * 2 + i) * 512;
  }
  const u16* pb[4]; int lob[4];
#pragma unroll
  for (int i = 0; i < 4; i++) {
    const int row = (wid * 4 + i) * 8 + lr8;          // 0..127
    pb[i] = w1t + ((size_t)e * H_DIM + n0 + row) * D_DIM + kperm;
    lob[i] = (wid * 4 + i) * 512;
  }

  f32x4 acc[2][4];
#pragma unroll
  for (int i = 0; i < 2; i++)
#pragma unroll
    for (int j = 0; j < 4; j++) acc[i][j] = (f32x4){0.f, 0.f, 0.f, 0.f};

  auto stage = [&](int k0, int b) {   // 6 gload_lds per thread
#pragma unroll
    for (int i = 0; i < 2; i++) gload16(pa[i] + k0, &At[b][loa[i]]);
#pragma unroll
    for (int i = 0; i < 4; i++) gload16(pb[i] + k0, &Bt[b][lob[i]]);
  };

  stage(0, 0);
  const int nt = D_DIM / 64;   // 8
  int cur = 0;
  for (int t = 0; t < nt; ++t) {
    asm volatile("s_waitcnt vmcnt(0)" ::: "memory");   // stage(t) resident (issued last step)
    __builtin_amdgcn_sched_barrier(0);
    __builtin_amdgcn_s_barrier();                      // all waves: buf[cur] ready, buf[cur^1] free
    if (t + 1 < nt) stage((t + 1) * 64, cur ^ 1);      // issue early; hides under ds_read+MFMA
    bf16x8 afr[2][2], bfr[4][2];
#pragma unroll
    for (int ks = 0; ks < 2; ks++) {
#pragma unroll
      for (int fq = 0; fq < 2; fq++)
        afr[fq][ks] = *(const bf16x8*)(&At[cur][(wr * 32 + fq * 16 + lrow) * 64 + ((ks * 4 + lk) ^ sx) * 8]);
#pragma unroll
      for (int fq = 0; fq < 4; fq++)
        bfr[fq][ks] = *(const bf16x8*)(&Bt[cur][(wc * 64 + fq * 16 + lrow) * 64 + ((ks * 4 + lk) ^ sx) * 8]);
    }
    asm volatile("s_waitcnt lgkmcnt(0)" ::: "memory"); // reads of buf[cur] drained before next barrier
    __builtin_amdgcn_sched_barrier(0);
    __builtin_amdgcn_s_setprio(1);
#pragma unroll
    for (int ks = 0; ks < 2; ks++)
#pragma unroll
      for (int fr = 0; fr < 2; fr++)
#pragma unroll
        for (int fc = 0; fc < 4; fc++)
          acc[fr][fc] = __builtin_amdgcn_mfma_f32_16x16x32_bf16(afr[fr][ks], bfr[fc][ks], acc[fr][fc], 0, 0, 0);
    __builtin_amdgcn_s_setprio(0);
    cur ^= 1;
  }

  float bias[4];
#pragma unroll
  for (int fc = 0; fc < 4; fc++) bias[fc] = b1[e * H_DIM + n0 + wc * 64 + fc * 16 + lrow];
#pragma unroll
  for (int fr = 0; fr < 2; fr++) {
#pragma unroll
    for (int reg = 0; reg < 4; reg++) {
      const int rloc = wr * 32 + fr * 16 + lk * 4 + reg;
      const int grow = rbase + rloc;
      if (grow < cnt) {
        const int slot = slot_list[e * CAP + grow];
        const float p  = prob_list[e * CAP + grow];
        u16* dst = hbuf + (size_t)slot * H_DIM + n0 + wc * 64 + lrow;
#pragma unroll
        for (int fc = 0; fc < 4; fc++) {
          float v = acc[fr][fc][reg] + bias[fc];
          dst[fc * 16] = f2bf(gelu_fast(v) * p);
        }
      }
    }
  }
}

// ---------------- grouped GEMM2: out[t] += h @ w2 + p*b2 (atomic f32, 2 addends) --------
// tile 64x128, BK=64, 2-buffer single-barrier loop, T2 swizzle, 48KB -> 3 blocks/CU
// grid: dim3(4, E*64)
__global__ __launch_bounds__(256, 3) void gemm2_kernel(const u16* __restrict__ hbuf,  // [2T][H]
                                                       const u16* __restrict__ w2t,   // [E][D][H]
                                                       const float* __restrict__ b2,  // [E][D]
                                                       const int* __restrict__ slot_list,
                                                       const float* __restrict__ prob_list,
                                                       const int* __restrict__ counts,
                                                       float* __restrict__ out) {     // [T][D]
  const int e  = blockIdx.y >> 6;
  const int rt = blockIdx.y & 63;
  const int cnt = counts[e];
  const int rbase = rt * 64;
  if (rbase >= cnt) return;
  const int n0 = blockIdx.x * 128;

  __shared__ __align__(16) u16 At[2][64 * 64];
  __shared__ __align__(16) u16 Bt[2][128 * 64];

  const int tid = threadIdx.x, lane = tid & 63, wid = tid >> 6;
  const int wr = wid >> 1, wc = wid & 1;
  const int lr8 = lane >> 3;
  const int sx = lane & 7;
  const int kperm = (sx ^ lr8) * 8;
  const int lrow = lane & 15, lk = lane >> 4;

  const u16* pa[2]; int loa[2];
#pragma unroll
  for (int i = 0; i < 2; i++) {
    const int row = (wid * 2 + i) * 8 + lr8;          // 0..63
    const int grow = rbase + row;
    int slot = 0;
    if (grow < cnt) slot = slot_list[e * CAP + grow];
    pa[i] = hbuf + (size_t)slot * H_DIM + kperm;
    loa[i] = (wid * 2 + i) * 512;
  }
  const u16* pb[4]; int lob[4];
#pragma unroll
  for (int i = 0; i < 4; i++) {
    const int row = (wid * 4 + i) * 8 + lr8;          // 0..127
    pb[i] = w2t + ((size_t)e * D_DIM + n0 + row) * H_DIM + kperm;
    lob[i] = (wid * 4 + i) * 512;
  }

  f32x4 acc[2][4];
#pragma unroll
  for (int i = 0; i < 2; i++)
#pragma unroll
    for (int j = 0; j < 4; j++) acc[i][j] = (f32x4){0.f, 0.f, 0.f, 0.f};

  auto stage = [&](int k0, int b) {   // 6 gload_lds per thread
#pragma unroll
    for (int i = 0; i < 2; i++) gload16(pa[i] + k0, &At[b][loa[i]]);
#pragma unroll
    for (int i = 0; i < 4; i++) gload16(pb[i] + k0, &Bt[b][lob[i]]);
  };

  stage(0, 0);
  const int nt = H_DIM / 64;   // 32
  int cur = 0;
  for (int t = 0; t < nt; ++t) {
    asm volatile("s_waitcnt vmcnt(0)" ::: "memory");
    __builtin_amdgcn_sched_barrier(0);
    __builtin_amdgcn_s_barrier();
    if (t + 1 < nt) stage((t + 1) * 64, cur ^ 1);
    bf16x8 afr[2][2], bfr[4][2];
#pragma unroll
    for (int ks = 0; ks < 2; ks++) {
#pragma unroll
      for (int fq = 0; fq < 2; fq++)
        afr[fq][ks] = *(const bf16x8*)(&At[cur][(wr * 32 + fq * 16 + lrow) * 64 + ((ks * 4 + lk) ^ sx) * 8]);
#pragma unroll
      for (int fq = 0; fq < 4; fq++)
        bfr[fq][ks] = *(const bf16x8*)(&Bt[cur][(wc * 64 + fq * 16 + lrow) * 64 + ((ks * 4 + lk) ^ sx) * 8]);
    }
    asm volatile("s_waitcnt lgkmcnt(0)" ::: "memory");
    __builtin_amdgcn_sched_barrier(0);
    __builtin_amdgcn_s_setprio(1);
#pragma unroll
    for (int ks = 0; ks < 2; ks++)
#pragma unroll
      for (int fr = 0; fr < 2; fr++)
#pragma unroll
        for (int fc = 0; fc < 4; fc++)
          acc[fr][fc] = __builtin_amdgcn_mfma_f32_16x16x32_bf16(afr[fr][ks], bfr[fc][ks], acc[fr][fc], 0, 0, 0);
    __builtin_amdgcn_s_setprio(0);
    cur ^= 1;
  }

  // epilogue: out[token] += acc + p*b2 (exactly 2 atomic addends per element -> deterministic)
#pragma unroll
  for (int fr = 0; fr < 2; fr++) {
#pragma unroll
    for (int reg = 0; reg < 4; reg++) {
      const int rloc = wr * 32 + fr * 16 + lk * 4 + reg;
      const int grow = rbase + rloc;
      if (grow < cnt) {
        const int slot = slot_list[e * CAP + grow];
        const float p  = prob_list[e * CAP + grow];
        float* dst = out + (size_t)(slot >> 1) * D_DIM + n0 + wc * 64 + lrow;
#pragma unroll
        for (int fc = 0; fc < 4; fc++) {
          float v = acc[fr][fc][reg] + p * b2[e * D_DIM + n0 + wc * 64 + fc * 16 + lrow];
          atomicAdd(&dst[fc * 16], v);
        }
      }
    }
  }
}

extern "C" void kernel_launch(void* const* d_in, const int* in_sizes, int n_in,
                              void* d_out, int out_size, void* d_ws, size_t ws_size,
                              hipStream_t stream) {
  const float* x  = (const float*)d_in[0];
  const float* w1 = (const float*)d_in[1];
  const float* w2 = (const float*)d_in[2];
  const float* b1 = (const float*)d_in[3];
  const float* b2 = (const float*)d_in[4];
  const float* rw = (const float*)d_in[5];
  const float* rb = (const float*)d_in[6];
  float* out = (float*)d_out;

  char* ws = (char*)d_ws;
  size_t off = 0;
  auto alloc = [&](size_t bytes) -> void* {
    void* p = ws + off;
    off = (off + bytes + 255) & ~(size_t)255;
    return p;
  };
  int*   counts    = (int*)alloc(E_NUM * 4);
  int*   chunkcnt  = (int*)alloc(NCHUNK * E_NUM * 4);
  int*   slot_list = (int*)alloc((size_t)E_NUM * CAP * 4);
  float* prob_list = (float*)alloc((size_t)E_NUM * CAP * 4);
  int*   topk_idx  = (int*)alloc((size_t)T_TOKENS * 2 * 4);
  float* topk_p    = (float*)alloc((size_t)T_TOKENS * 2 * 4);
  u16*   xb        = (u16*)alloc((size_t)T_TOKENS * D_DIM * 2);
  u16*   w1t       = (u16*)alloc((size_t)E_NUM * H_DIM * D_DIM * 2);
  u16*   w2t       = (u16*)alloc((size_t)E_NUM * H_DIM * D_DIM * 2);
  u16*   hbuf      = (u16*)alloc((size_t)NSLOT * H_DIM * 2);

  transpose_both_kernel<<<4096, 256, 0, stream>>>(w1, w2, w1t, w2t);
  router_kernel<<<T_TOKENS / 4, 256, 0, stream>>>(x, rw, rb, topk_idx, topk_p, xb, out);
  count_kernel<<<NCHUNK, 256, 0, stream>>>(topk_idx, chunkcnt);
  scatter_kernel<<<NCHUNK * E_NUM, 256, 0, stream>>>(topk_idx, topk_p, chunkcnt, slot_list, prob_list, counts);
  gemm1_kernel<<<dim3(16, E_NUM * 64), 256, 0, stream>>>(xb, w1t, b1, slot_list, prob_list, counts, hbuf);
  gemm2_kernel<<<dim3(4, E_NUM * 64), 256, 0, stream>>>(hbuf, w2t, b2, slot_list, prob_list, counts, out);
}